// Round 18
// baseline (142.044 us; speedup 1.0000x reference)
//
#include <hip/hip_runtime.h>
#include <math.h>

#define NN 2048
#define CC 128
#define HH 8
#define DD 16
#define NKEY 128
#define INFV 1e8f
#define NPR ((long)NN * CC / 4)
#define NCPTOT (NPR + (long)NN * NN * 4)
#define SLOT 2176   // 32x68 fp32 tile (64-wide B / 64-row A)
#define ANP 36      // 32-row A tile pad
#define ASLOT 1152  // 32x36
#define GRID 4096   // finer granularity -> tighter CU self-balancing

typedef float f4 __attribute__((ext_vector_type(4)));  // native vec for nontemporal builtins
typedef unsigned short bf16;

__device__ __forceinline__ float sigm(float x) { return 1.f / (1.f + expf(-x)); }
__device__ __forceinline__ bf16 f2b(float x) {
  unsigned u = __float_as_uint(x);
  u += 0x7FFF + ((u >> 16) & 1);   // round to nearest even
  return (bf16)(u >> 16);
}
__device__ __forceinline__ float b2f(bf16 b) {
  return __uint_as_float(((unsigned)b) << 16);
}

struct Args {
  const float *atom_single, *atom_proj, *atom_pair, *mask;
  const float *a_sln_w, *a_gate_w, *a_gate_b, *a_skip_w;
  const float *wq, *bq, *wk, *wv, *wg, *bg, *wo, *bo;
  const float *lnz_w, *lnz_b, *wz, *wog, *bog;
  const float *t_sln_w, *t_gate_w, *t_gate_b, *t_skip_w;
  const float *w_sw, *w_hid, *w_out, *t_wog, *t_bog;
  float *out;
  bf16 *s_ln_t, *a_mat, *qm, *km, *vm, *gm, *ogm, *t_mat, *hidden, *bias;
  float *single2;
  long cut[8];
};

// ---------------------------------------------------------------------------
// Copy ballast (nontemporal — round-16 verified win).
// ---------------------------------------------------------------------------
__device__ __forceinline__ void copy_span(const Args& a, int s, long rb, long nb, int tid) {
  long c0 = a.cut[s], c1 = a.cut[s + 1];
  const f4* proj4 = (const f4*)a.atom_proj;
  const f4* pair4 = (const f4*)a.atom_pair;
  f4* dst = (f4*)(a.out + (long)NN * CC);
  long stride = nb * 256;
  long i = c0 + rb * 256 + tid;
  for (; i + 3 * stride < c1; i += 4 * stride) {
    long i1 = i + stride, i2 = i + 2 * stride, i3 = i + 3 * stride;
    f4 x0 = (i  < NPR) ? __builtin_nontemporal_load(&proj4[i])
                       : __builtin_nontemporal_load(&pair4[i - NPR]);
    f4 x1 = (i1 < NPR) ? __builtin_nontemporal_load(&proj4[i1])
                       : __builtin_nontemporal_load(&pair4[i1 - NPR]);
    f4 x2 = (i2 < NPR) ? __builtin_nontemporal_load(&proj4[i2])
                       : __builtin_nontemporal_load(&pair4[i2 - NPR]);
    f4 x3 = (i3 < NPR) ? __builtin_nontemporal_load(&proj4[i3])
                       : __builtin_nontemporal_load(&pair4[i3 - NPR]);
    __builtin_nontemporal_store(x0, &dst[i]);
    __builtin_nontemporal_store(x1, &dst[i1]);
    __builtin_nontemporal_store(x2, &dst[i2]);
    __builtin_nontemporal_store(x3, &dst[i3]);
  }
  for (; i < c1; i += stride) {
    f4 v = (i < NPR) ? __builtin_nontemporal_load(&proj4[i])
                     : __builtin_nontemporal_load(&pair4[i - NPR]);
    __builtin_nontemporal_store(v, &dst[i]);
  }
}

// ---------------------------------------------------------------------------
// 64x64 single-GEMM (qkvg), BK=32, DEPTH-2 prefetch; A operand bf16.
// ---------------------------------------------------------------------------
__device__ __forceinline__ void gsingle_pf(float* sm, int tid,
    const bf16* __restrict__ A1, const float* __restrict__ B1, int lda1, int ldb1, int K1,
    int r0, int c0, float acc1[4][4]) {
  float* buf0 = sm;
  float* buf1 = sm + 2 * SLOT;
  int tr = (tid >> 4) * 4, tc = (tid & 15) * 4;
  int ar = tid >> 5, ak = tid & 31;
  int bk = tid >> 6, bc = tid & 63;
  float pA[2][8], pB[2][8];
  auto LD = [&](int kb, int s) {
#pragma unroll
    for (int j = 0; j < 8; ++j) {
      pA[s][j] = b2f(A1[(long)(r0 + ar + 8 * j) * lda1 + kb + ak]);
      pB[s][j] = B1[(long)(kb + bk + 4 * j) * ldb1 + c0 + bc];
    }
  };
  auto WR = [&](float* buf, int s) {
    float* B1s_ = buf + SLOT;
#pragma unroll
    for (int j = 0; j < 8; ++j) {
      buf[ak * 68 + ar + 8 * j] = pA[s][j];
      B1s_[(bk + 4 * j) * 68 + bc] = pB[s][j];
    }
  };
  auto CMP = [&](float* cur) {
    float* As_ = cur;
    float* B1s_ = cur + SLOT;
#pragma unroll 4
    for (int k = 0; k < 32; ++k) {
      float4 a1 = *(const float4*)&As_[k * 68 + tr];
      float4 b1 = *(const float4*)&B1s_[k * 68 + tc];
      float a1v[4] = {a1.x, a1.y, a1.z, a1.w};
      float b1v[4] = {b1.x, b1.y, b1.z, b1.w};
#pragma unroll
      for (int i = 0; i < 4; ++i)
#pragma unroll
        for (int j = 0; j < 4; ++j) acc1[i][j] = fmaf(a1v[i], b1v[j], acc1[i][j]);
    }
  };
  int nk = K1 / 32;
  LD(0, 0);
  if (nk > 1) LD(32, 1);
  WR(buf0, 0);
  __syncthreads();
  for (int kt = 0; kt < nk; kt += 2) {
    if (kt + 2 < nk) LD((kt + 2) * 32, 0);
    if (kt + 1 < nk) WR(buf1, 1);
    CMP(buf0);
    __syncthreads();
    if (kt + 1 >= nk) break;
    if (kt + 3 < nk) LD((kt + 3) * 32, 1);
    if (kt + 2 < nk) WR(buf0, 0);
    CMP(buf1);
    __syncthreads();
  }
}

// ---------------------------------------------------------------------------
// 32x64 dual-GEMM, BK=32, DEPTH-2 prefetch. BF1: A1 stored bf16 (A2 always f32).
// ---------------------------------------------------------------------------
template <bool SHA, bool BF1>
__device__ __forceinline__ void gdual32(float* sm, int tid,
    const void* A1v, const float* __restrict__ B1, int lda1, int ldb1, int K1,
    const float* __restrict__ A2, const float* __restrict__ B2, int lda2, int ldb2, int K2,
    int r0, int c0, float acc1[2][4], float acc2[2][4]) {
  const int offB1 = ASLOT;
  const int offA2 = ASLOT + SLOT;
  const int offB2 = SHA ? (ASLOT + SLOT) : (2 * ASLOT + SLOT);
  const int bufsz = SHA ? (ASLOT + 2 * SLOT) : (2 * ASLOT + 2 * SLOT);
  const float* A1f = (const float*)A1v;
  const bf16* A1b = (const bf16*)A1v;
  float* buf0 = sm;
  float* buf1 = sm + bufsz;
  int tr2 = (tid >> 4) * 2, tc4 = (tid & 15) * 4;
  int ar = tid & 31, ak4 = (tid >> 5) * 4;
  int bk = tid >> 6, bc = tid & 63;
  float4 vA1[2], vA2[2];
  float pB1[2][8], pB2[2][8];

  auto LD = [&](int kb, int s, bool twof) {
    if constexpr (BF1) {
      ushort4 rw = *(const ushort4*)&A1b[(long)(r0 + ar) * lda1 + kb + ak4];
      vA1[s] = make_float4(b2f(rw.x), b2f(rw.y), b2f(rw.z), b2f(rw.w));
    } else {
      vA1[s] = *(const float4*)&A1f[(long)(r0 + ar) * lda1 + kb + ak4];
    }
#pragma unroll
    for (int j = 0; j < 8; ++j)
      pB1[s][j] = B1[(long)(kb + bk + 4 * j) * ldb1 + c0 + bc];
    if (twof) {
      if constexpr (!SHA) vA2[s] = *(const float4*)&A2[(long)(r0 + ar) * lda2 + kb + ak4];
#pragma unroll
      for (int j = 0; j < 8; ++j)
        pB2[s][j] = B2[(long)(kb + bk + 4 * j) * ldb2 + c0 + bc];
    }
  };
  auto WR = [&](float* buf, int s, bool twof) {
    float* As_ = buf;
    float* B1s_ = buf + offB1;
    As_[(ak4 + 0) * ANP + ar] = vA1[s].x;
    As_[(ak4 + 1) * ANP + ar] = vA1[s].y;
    As_[(ak4 + 2) * ANP + ar] = vA1[s].z;
    As_[(ak4 + 3) * ANP + ar] = vA1[s].w;
#pragma unroll
    for (int j = 0; j < 8; ++j) B1s_[(bk + 4 * j) * 68 + bc] = pB1[s][j];
    if (twof) {
      float* B2s_ = buf + offB2;
      if constexpr (!SHA) {
        float* A2s_ = buf + offA2;
        A2s_[(ak4 + 0) * ANP + ar] = vA2[s].x;
        A2s_[(ak4 + 1) * ANP + ar] = vA2[s].y;
        A2s_[(ak4 + 2) * ANP + ar] = vA2[s].z;
        A2s_[(ak4 + 3) * ANP + ar] = vA2[s].w;
      }
#pragma unroll
      for (int j = 0; j < 8; ++j) B2s_[(bk + 4 * j) * 68 + bc] = pB2[s][j];
    }
  };
  auto CMP = [&](float* cur, bool twoc) {
    float* As_ = cur;
    float* B1s_ = cur + offB1;
    float* A2s_ = cur + offA2;
    float* B2s_ = cur + offB2;
    if (twoc) {
#pragma unroll 4
      for (int k = 0; k < 32; ++k) {
        float2 a1 = *(const float2*)&As_[k * ANP + tr2];
        float4 b1 = *(const float4*)&B1s_[k * 68 + tc4];
        float4 b2 = *(const float4*)&B2s_[k * 68 + tc4];
        float2 a2;
        if constexpr (SHA) a2 = a1; else a2 = *(const float2*)&A2s_[k * ANP + tr2];
        float a1v[2] = {a1.x, a1.y};
        float a2v[2] = {a2.x, a2.y};
        float b1v[4] = {b1.x, b1.y, b1.z, b1.w};
        float b2v[4] = {b2.x, b2.y, b2.z, b2.w};
#pragma unroll
        for (int i = 0; i < 2; ++i)
#pragma unroll
          for (int j = 0; j < 4; ++j) {
            acc1[i][j] = fmaf(a1v[i], b1v[j], acc1[i][j]);
            acc2[i][j] = fmaf(a2v[i], b2v[j], acc2[i][j]);
          }
      }
    } else {
#pragma unroll 4
      for (int k = 0; k < 32; ++k) {
        float2 a1 = *(const float2*)&As_[k * ANP + tr2];
        float4 b1 = *(const float4*)&B1s_[k * 68 + tc4];
        float a1v[2] = {a1.x, a1.y};
        float b1v[4] = {b1.x, b1.y, b1.z, b1.w};
#pragma unroll
        for (int i = 0; i < 2; ++i)
#pragma unroll
          for (int j = 0; j < 4; ++j) acc1[i][j] = fmaf(a1v[i], b1v[j], acc1[i][j]);
      }
    }
  };

  int nk = K1 / 32;
  LD(0, 0, 0 < K2);
  if (nk > 1) LD(32, 1, 32 < K2);
  WR(buf0, 0, 0 < K2);
  __syncthreads();
  for (int kt = 0; kt < nk; kt += 2) {
    if (kt + 2 < nk) LD((kt + 2) * 32, 0, (kt + 2) * 32 < K2);
    if (kt + 1 < nk) WR(buf1, 1, (kt + 1) * 32 < K2);
    CMP(buf0, kt * 32 < K2);
    __syncthreads();
    if (kt + 1 >= nk) break;
    if (kt + 3 < nk) LD((kt + 3) * 32, 1, (kt + 3) * 32 < K2);
    if (kt + 2 < nk) WR(buf0, 0, (kt + 2) * 32 < K2);
    CMP(buf1, (kt + 1) * 32 < K2);
    __syncthreads();
  }
}

// ---------------------------------------------------------------------------
// gdual32_ln: SHA-dual-GEMM, A = LN(proj)*w_ln on the fly (round-14 verified).
// ---------------------------------------------------------------------------
__device__ __forceinline__ void gdual32_ln(float* sm, int tid,
    const float* __restrict__ proj, const float* __restrict__ w_ln,
    const float* __restrict__ B1, const float* __restrict__ B2,
    int r0, int c0, const float* sst, float acc1[2][4], float acc2[2][4]) {
  const int offB1 = ASLOT;
  const int offB2 = ASLOT + SLOT;
  const int bufsz = ASLOT + 2 * SLOT;
  float* buf0 = sm;
  float* buf1 = sm + bufsz;
  int tr2 = (tid >> 4) * 2, tc4 = (tid & 15) * 4;
  int ar = tid & 31, ak4 = (tid >> 5) * 4;
  int bk = tid >> 6, bc = tid & 63;
  float4 vA1[2];
  float pB1[2][8], pB2[2][8];

  auto LD = [&](int kb, int s) {
    float4 raw = *(const float4*)&proj[(long)(r0 + ar) * CC + kb + ak4];
    float4 wv = *(const float4*)&w_ln[kb + ak4];
    float mu = sst[2 * ar], rs = sst[2 * ar + 1];
    vA1[s].x = (raw.x - mu) * rs * wv.x;
    vA1[s].y = (raw.y - mu) * rs * wv.y;
    vA1[s].z = (raw.z - mu) * rs * wv.z;
    vA1[s].w = (raw.w - mu) * rs * wv.w;
#pragma unroll
    for (int j = 0; j < 8; ++j) {
      pB1[s][j] = B1[(long)(kb + bk + 4 * j) * CC + c0 + bc];
      pB2[s][j] = B2[(long)(kb + bk + 4 * j) * CC + c0 + bc];
    }
  };
  auto WR = [&](float* buf, int s) {
    float* B1s_ = buf + offB1;
    float* B2s_ = buf + offB2;
    buf[(ak4 + 0) * ANP + ar] = vA1[s].x;
    buf[(ak4 + 1) * ANP + ar] = vA1[s].y;
    buf[(ak4 + 2) * ANP + ar] = vA1[s].z;
    buf[(ak4 + 3) * ANP + ar] = vA1[s].w;
#pragma unroll
    for (int j = 0; j < 8; ++j) {
      B1s_[(bk + 4 * j) * 68 + bc] = pB1[s][j];
      B2s_[(bk + 4 * j) * 68 + bc] = pB2[s][j];
    }
  };
  auto CMP = [&](float* cur) {
    float* As_ = cur;
    float* B1s_ = cur + offB1;
    float* B2s_ = cur + offB2;
#pragma unroll 4
    for (int k = 0; k < 32; ++k) {
      float2 a1 = *(const float2*)&As_[k * ANP + tr2];
      float4 b1 = *(const float4*)&B1s_[k * 68 + tc4];
      float4 b2 = *(const float4*)&B2s_[k * 68 + tc4];
      float a1v[2] = {a1.x, a1.y};
      float b1v[4] = {b1.x, b1.y, b1.z, b1.w};
      float b2v[4] = {b2.x, b2.y, b2.z, b2.w};
#pragma unroll
      for (int i = 0; i < 2; ++i)
#pragma unroll
        for (int j = 0; j < 4; ++j) {
          acc1[i][j] = fmaf(a1v[i], b1v[j], acc1[i][j]);
          acc2[i][j] = fmaf(a1v[i], b2v[j], acc2[i][j]);
        }
    }
  };

  LD(0, 0);
  LD(32, 1);
  WR(buf0, 0);
  __syncthreads();
  LD(64, 0);
  WR(buf1, 1);
  CMP(buf0);
  __syncthreads();
  LD(96, 1);
  WR(buf0, 0);
  CMP(buf1);
  __syncthreads();
  WR(buf1, 1);
  CMP(buf0);
  __syncthreads();
  CMP(buf1);
  __syncthreads();
}

// ---------------------------------------------------------------------------
// Stage bodies
// ---------------------------------------------------------------------------
__device__ __forceinline__ void bias_stage(const Args& a, long lo, long hi,
                                           int bid, int nb, int tid, float* sm) {
  float* swz = sm;
  float* swn = sm + 128;
  float* sbn = sm + 144;
  if (tid < 128) swz[tid] = a.wz[tid];
  else if (tid < 144) swn[tid - 128] = a.lnz_w[tid - 128];
  else if (tid < 160) sbn[tid - 144] = a.lnz_b[tid - 144];
  __syncthreads();
  for (long e = lo + bid * 256 + tid; e < hi; e += (long)nb * 256) {
    int q = (int)(e >> 7), kk = (int)(e & 127);
    int k = (q >> 5) * 32 - 48 + kk;
    float o[HH];
    if (k >= 0 && k < NN) {
      const float4* p = (const float4*)(a.atom_pair + ((long)q * NN + k) * 16);
      float4 x0 = p[0], x1 = p[1], x2 = p[2], x3 = p[3];
      float x[16] = {x0.x, x0.y, x0.z, x0.w, x1.x, x1.y, x1.z, x1.w,
                     x2.x, x2.y, x2.z, x2.w, x3.x, x3.y, x3.z, x3.w};
      float s = 0.f, ss = 0.f;
#pragma unroll
      for (int c = 0; c < 16; ++c) { s += x[c]; ss += x[c] * x[c]; }
      float mu = s * (1.f / 16.f);
      float r = rsqrtf(ss * (1.f / 16.f) - mu * mu + 1e-5f);
#pragma unroll
      for (int h = 0; h < HH; ++h) o[h] = 0.f;
#pragma unroll
      for (int c = 0; c < 16; ++c) {
        float y = (x[c] - mu) * r * swn[c] + sbn[c];
#pragma unroll
        for (int h = 0; h < HH; ++h) o[h] = fmaf(y, swz[c * HH + h], o[h]);
      }
      float mb = INFV * (a.mask[k] - 1.f);
#pragma unroll
      for (int h = 0; h < HH; ++h) o[h] += mb;
    } else {
#pragma unroll
      for (int h = 0; h < HH; ++h) o[h] = -INFV;
    }
#pragma unroll
    for (int h = 0; h < HH; ++h) a.bias[(long)h * NN * NKEY + e] = f2b(o[h]);
  }
}

// adaln_a with inline LN (round-14 verified); bf16 outputs.
__device__ __forceinline__ void adaln_a_ln(const Args& a, int bid, int tid,
                                           float* sm, float* sst) {
  int r0 = (bid & 63) * 32, c0 = (bid >> 6) * 64;
  {
    int row = tid >> 3, cg = (tid & 7) * 16;
    const float* sp = a.atom_proj + (long)(r0 + row) * CC + cg;
    const float* ss_ = a.atom_single + (long)(r0 + row) * CC + cg;
    float s1 = 0.f, q1 = 0.f, s2 = 0.f, q2 = 0.f;
#pragma unroll
    for (int j = 0; j < 4; ++j) {
      float4 v = *(const float4*)(sp + j * 4);
      s1 += v.x + v.y + v.z + v.w;
      q1 += v.x * v.x + v.y * v.y + v.z * v.z + v.w * v.w;
      float4 u = *(const float4*)(ss_ + j * 4);
      s2 += u.x + u.y + u.z + u.w;
      q2 += u.x * u.x + u.y * u.y + u.z * u.z + u.w * u.w;
    }
#pragma unroll
    for (int m = 1; m < 8; m <<= 1) {
      s1 += __shfl_xor(s1, m); q1 += __shfl_xor(q1, m);
      s2 += __shfl_xor(s2, m); q2 += __shfl_xor(q2, m);
    }
    if ((tid & 7) == 0) {
      float mu1 = s1 * (1.f / CC);
      sst[2 * row] = mu1;
      sst[2 * row + 1] = rsqrtf(q1 * (1.f / CC) - mu1 * mu1 + 1e-5f);
      float mu2 = s2 * (1.f / CC);
      sst[64 + 2 * row] = mu2;
      sst[64 + 2 * row + 1] = rsqrtf(q2 * (1.f / CC) - mu2 * mu2 + 1e-5f);
    }
  }
  __syncthreads();
  float acc1[2][4] = {{0}}, acc2[2][4] = {{0}};
  gdual32_ln(sm, tid, a.atom_proj, a.a_sln_w, a.a_gate_w, a.a_skip_w,
             r0, c0, sst, acc1, acc2);
  int tr2 = (tid >> 4) * 2, tc4 = (tid & 15) * 4;
#pragma unroll
  for (int i = 0; i < 2; ++i) {
    long r = r0 + tr2 + i;
    float mup = sst[2 * (tr2 + i)], rsp = sst[2 * (tr2 + i) + 1];
    float mus = sst[64 + 2 * (tr2 + i)], rss = sst[64 + 2 * (tr2 + i) + 1];
    float4 sv = *(const float4*)(a.atom_single + r * CC + c0 + tc4);
    float4 pv = *(const float4*)(a.atom_proj + r * CC + c0 + tc4);
    float4 wt = *(const float4*)(a.t_sln_w + c0 + tc4);
    float lnm[4] = {(sv.x - mus) * rss, (sv.y - mus) * rss,
                    (sv.z - mus) * rss, (sv.w - mus) * rss};
    float lnp[4] = {(pv.x - mup) * rsp, (pv.y - mup) * rsp,
                    (pv.z - mup) * rsp, (pv.w - mup) * rsp};
    float wtv[4] = {wt.x, wt.y, wt.z, wt.w};
    float o[4];
#pragma unroll
    for (int j = 0; j < 4; ++j)
      o[j] = sigm(acc1[i][j] + a.a_gate_b[c0 + tc4 + j]) * lnm[j] + acc2[i][j];
    *(ushort4*)(a.a_mat + r * CC + c0 + tc4) =
        make_ushort4(f2b(o[0]), f2b(o[1]), f2b(o[2]), f2b(o[3]));
    *(ushort4*)(a.s_ln_t + r * CC + c0 + tc4) =
        make_ushort4(f2b(lnp[0] * wtv[0]), f2b(lnp[1] * wtv[1]),
                     f2b(lnp[2] * wtv[2]), f2b(lnp[3] * wtv[3]));
  }
}

// adaln_t: A = s_ln_t (bf16), gate multiplier = inline LN(single2 f32).
__device__ __forceinline__ void adaln_t_stage(const Args& a, int bid, int tid,
                                              float* sm, float* sst) {
  int r0 = (bid & 63) * 32, c0 = (bid >> 6) * 64;
  {
    int row = tid >> 3, cg = (tid & 7) * 16;
    const float* src = a.single2 + (long)(r0 + row) * CC + cg;
    float s = 0.f, ss = 0.f;
#pragma unroll
    for (int j = 0; j < 4; ++j) {
      float4 v = *(const float4*)(src + j * 4);
      s += v.x + v.y + v.z + v.w;
      ss += v.x * v.x + v.y * v.y + v.z * v.z + v.w * v.w;
    }
#pragma unroll
    for (int m = 1; m < 8; m <<= 1) { s += __shfl_xor(s, m); ss += __shfl_xor(ss, m); }
    if ((tid & 7) == 0) {
      float mu = s * (1.f / CC);
      sst[2 * row] = mu;
      sst[2 * row + 1] = rsqrtf(ss * (1.f / CC) - mu * mu + 1e-5f);
    }
  }
  float acc1[2][4] = {{0}}, acc2[2][4] = {{0}};
  gdual32<true, true>(sm, tid, a.s_ln_t, a.t_gate_w, 128, 128, 128,
                      nullptr, a.t_skip_w, 128, 128, 128, r0, c0, acc1, acc2);
  int tr2 = (tid >> 4) * 2, tc4 = (tid & 15) * 4;
#pragma unroll
  for (int i = 0; i < 2; ++i) {
    long r = r0 + tr2 + i;
    float mu = sst[2 * (tr2 + i)], rr = sst[2 * (tr2 + i) + 1];
    float4 sv = *(const float4*)(a.single2 + r * CC + c0 + tc4);
    float lv[4] = {(sv.x - mu) * rr, (sv.y - mu) * rr, (sv.z - mu) * rr, (sv.w - mu) * rr};
    float o[4];
#pragma unroll
    for (int j = 0; j < 4; ++j)
      o[j] = sigm(acc1[i][j] + a.t_gate_b[c0 + tc4 + j]) * lv[j] + acc2[i][j];
    *(ushort4*)(a.t_mat + r * CC + c0 + tc4) =
        make_ushort4(f2b(o[0]), f2b(o[1]), f2b(o[2]), f2b(o[3]));
  }
}

__device__ __forceinline__ void gemm4_stage(const Args& a, int bid, int tid, float* sm) {
  int r0 = (bid & 31) * 64;
  int cg4 = (bid >> 5) * 64;
  int mat = cg4 >> 7;
  int c0 = cg4 & 127;
  const float* B = (mat == 0) ? a.wq : (mat == 1) ? a.wk : (mat == 2) ? a.wv : a.wg;
  float acc[4][4] = {{0}};
  gsingle_pf(sm, tid, a.a_mat, B, 128, 128, 128, r0, c0, acc);
  bf16* outp = (mat == 0) ? a.qm : (mat == 1) ? a.km : (mat == 2) ? a.vm : a.gm;
  int tr = (tid >> 4) * 4, tc = (tid & 15) * 4;
#pragma unroll
  for (int i = 0; i < 4; ++i) {
    long r = r0 + tr + i;
    float o[4];
#pragma unroll
    for (int j = 0; j < 4; ++j) {
      float x = acc[i][j];
      if (mat == 0) x += a.bq[c0 + tc + j];
      if (mat == 3) x = sigm(x + a.bg[c0 + tc + j]);
      o[j] = x;
    }
    *(ushort4*)(outp + r * CC + c0 + tc) =
        make_ushort4(f2b(o[0]), f2b(o[1]), f2b(o[2]), f2b(o[3]));
  }
}

__device__ __forceinline__ void attn_unit(const Args& a, int u, int tid, float* sm) {
  int w = u & 63, h = u >> 6;
  int q0 = w * 32, k0 = w * 32 - 48;
  float* Qs = sm;
  float* Ks = sm + 544;
  float* Vs = sm + 3104;
  float* Ps = sm + 5664;
  for (int i = tid; i < 32 * 16; i += 256) {
    int qi = i >> 4, d = i & 15;
    Qs[qi * 17 + d] = b2f(a.qm[(long)(q0 + qi) * CC + h * DD + d]);
  }
  for (int i = tid; i < 128 * 16; i += 256) {
    int kk = i >> 4, d = i & 15;
    int k = k0 + kk;
    bool ok = (k >= 0 && k < NN);
    Ks[kk * 20 + d] = ok ? b2f(a.km[(long)k * CC + h * DD + d]) : 0.f;
    Vs[kk * 20 + d] = ok ? b2f(a.vm[(long)k * CC + h * DD + d]) : 0.f;
  }
  __syncthreads();
  int qi = tid >> 3, kg = tid & 7;
  const bf16* brow = a.bias + (long)h * NN * NKEY + (long)(q0 + qi) * NKEY;
  float qreg[16];
#pragma unroll
  for (int d = 0; d < 16; ++d) qreg[d] = Qs[qi * 17 + d];
  float l[16];
#pragma unroll
  for (int j = 0; j < 16; ++j) {
    int kk = kg + 8 * j;
    const float4* kr = (const float4*)&Ks[kk * 20];
    float4 k0v = kr[0], k1v = kr[1], k2v = kr[2], k3v = kr[3];
    float acc = 0.f;
    acc = fmaf(qreg[0], k0v.x, acc);  acc = fmaf(qreg[1], k0v.y, acc);
    acc = fmaf(qreg[2], k0v.z, acc);  acc = fmaf(qreg[3], k0v.w, acc);
    acc = fmaf(qreg[4], k1v.x, acc);  acc = fmaf(qreg[5], k1v.y, acc);
    acc = fmaf(qreg[6], k1v.z, acc);  acc = fmaf(qreg[7], k1v.w, acc);
    acc = fmaf(qreg[8], k2v.x, acc);  acc = fmaf(qreg[9], k2v.y, acc);
    acc = fmaf(qreg[10], k2v.z, acc); acc = fmaf(qreg[11], k2v.w, acc);
    acc = fmaf(qreg[12], k3v.x, acc); acc = fmaf(qreg[13], k3v.y, acc);
    acc = fmaf(qreg[14], k3v.z, acc); acc = fmaf(qreg[15], k3v.w, acc);
    l[j] = acc * 0.25f + b2f(brow[kk]);
  }
  float m = l[0];
#pragma unroll
  for (int j = 1; j < 16; ++j) m = fmaxf(m, l[j]);
#pragma unroll
  for (int mm = 1; mm < 8; mm <<= 1) m = fmaxf(m, __shfl_xor(m, mm));
  float sum = 0.f;
#pragma unroll
  for (int j = 0; j < 16; ++j) { l[j] = expf(l[j] - m); sum += l[j]; }
#pragma unroll
  for (int mm = 1; mm < 8; mm <<= 1) sum += __shfl_xor(sum, mm);
  float inv = 1.f / sum;
#pragma unroll
  for (int j = 0; j < 16; ++j) Ps[qi * 132 + kg + 8 * j] = l[j] * inv;
  __syncthreads();
  int d0 = tid & 7;
  float o0 = 0.f, o1 = 0.f;
#pragma unroll 8
  for (int kk = 0; kk < 128; ++kk) {
    float p = Ps[qi * 132 + kk];
    o0 = fmaf(p, Vs[kk * 20 + d0], o0);
    o1 = fmaf(p, Vs[kk * 20 + d0 + 8], o1);
  }
  long base = (long)(q0 + qi) * CC + h * DD;
  a.ogm[base + d0] = f2b(o0 * b2f(a.gm[base + d0]));
  a.ogm[base + d0 + 8] = f2b(o1 * b2f(a.gm[base + d0 + 8]));
}

__device__ __forceinline__ void out1_32(const Args& a, int bid, int tid, float* sm) {
  int r0 = (bid & 63) * 32, c0 = (bid >> 6) * 64;
  float accX[2][4] = {{0}}, accW[2][4] = {{0}};
  gdual32<false, true>(sm, tid, a.ogm, a.wo, 128, 128, 128,
                       a.atom_proj, a.wog, 128, 128, 128, r0, c0, accX, accW);
  int tr2 = (tid >> 4) * 2, tc4 = (tid & 15) * 4;
#pragma unroll
  for (int i = 0; i < 2; ++i) {
    long r = r0 + tr2 + i;
    float4 sv = *(const float4*)(a.atom_single + r * CC + c0 + tc4);
    float s[4] = {sv.x, sv.y, sv.z, sv.w};
    float o[4];
#pragma unroll
    for (int j = 0; j < 4; ++j) {
      int c = c0 + tc4 + j;
      o[j] = s[j] + sigm(accW[i][j] + a.bog[c]) * (accX[i][j] + a.bo[c]);
    }
    *(float4*)(a.single2 + r * CC + c0 + tc4) = make_float4(o[0], o[1], o[2], o[3]);
  }
}

__device__ __forceinline__ void swiglu_32(const Args& a, int bid, int tid, float* sm) {
  int r0 = (bid & 63) * 32, c0 = (bid >> 6) * 64;
  float acc1[2][4] = {{0}}, acc2[2][4] = {{0}};
  gdual32<true, true>(sm, tid, a.t_mat, a.w_sw, 128, 256, 128,
                      nullptr, a.w_hid, 128, 256, 128, r0, c0, acc1, acc2);
  int tr2 = (tid >> 4) * 2, tc4 = (tid & 15) * 4;
#pragma unroll
  for (int i = 0; i < 2; ++i) {
    long r = r0 + tr2 + i;
    float o[4];
#pragma unroll
    for (int j = 0; j < 4; ++j) {
      float x = acc1[i][j];
      o[j] = x * sigm(x) * acc2[i][j];
    }
    *(ushort4*)(a.hidden + r * 256 + c0 + tc4) =
        make_ushort4(f2b(o[0]), f2b(o[1]), f2b(o[2]), f2b(o[3]));
  }
}

__device__ __forceinline__ void out2_32(const Args& a, int bid, int tid, float* sm) {
  int r0 = (bid & 63) * 32, c0 = (bid >> 6) * 64;
  float accX[2][4] = {{0}}, accW[2][4] = {{0}};
  gdual32<false, true>(sm, tid, a.hidden, a.w_out, 256, 128, 256,
                       a.atom_proj, a.t_wog, 128, 128, 128, r0, c0, accX, accW);
  int tr2 = (tid >> 4) * 2, tc4 = (tid & 15) * 4;
#pragma unroll
  for (int i = 0; i < 2; ++i) {
    long r = r0 + tr2 + i;
    float4 sv = *(const float4*)(a.single2 + r * CC + c0 + tc4);
    float s[4] = {sv.x, sv.y, sv.z, sv.w};
    float o[4];
#pragma unroll
    for (int j = 0; j < 4; ++j) {
      int c = c0 + tc4 + j;
      o[j] = s[j] + sigm(accW[i][j] + a.t_bog[c]) * accX[i][j];
    }
    *(float4*)(a.out + r * CC + c0 + tc4) = make_float4(o[0], o[1], o[2], o[3]);
  }
}

// ---------------------------------------------------------------------------
// 7 kernels (round-17 verified structure), GRID=4096 for finer balancing.
// ---------------------------------------------------------------------------
#define BIAS_TOT ((long)NN * NKEY)
#define BIAS_H (BIAS_TOT / 2)

__global__ __launch_bounds__(256) void k_adaln_a(Args a) {
  __shared__ __align__(16) float sm[2 * (ASLOT + 2 * SLOT) + 128];
  int bid = blockIdx.x, tid = threadIdx.x;
  if (bid < 128) adaln_a_ln(a, bid, tid, sm, sm + 2 * (ASLOT + 2 * SLOT));
  else if (bid < 256) bias_stage(a, 0, BIAS_H, bid - 128, 128, tid, sm);
  else copy_span(a, 0, bid - 256, gridDim.x - 256, tid);
}

__global__ __launch_bounds__(256) void k_qkvg(Args a) {
  __shared__ __align__(16) float sm[2 * 2 * SLOT];
  int bid = blockIdx.x, tid = threadIdx.x;
  if (bid < 256) gemm4_stage(a, bid, tid, sm);
  else if (bid < 384) bias_stage(a, BIAS_H, BIAS_TOT, bid - 256, 128, tid, sm);
  else copy_span(a, 1, bid - 384, gridDim.x - 384, tid);
}

__global__ __launch_bounds__(256) void k_attn(Args a) {
  __shared__ __align__(16) float sm[9888];
  int bid = blockIdx.x, tid = threadIdx.x;
  if (bid < 512) attn_unit(a, bid, tid, sm);
  else copy_span(a, 2, bid - 512, gridDim.x - 512, tid);
}

__global__ __launch_bounds__(256) void k_out1(Args a) {
  __shared__ __align__(16) float sm[2 * (2 * ASLOT + 2 * SLOT)];
  int bid = blockIdx.x, tid = threadIdx.x;
  if (bid < 128) out1_32(a, bid, tid, sm);
  else copy_span(a, 3, bid - 128, gridDim.x - 128, tid);
}

__global__ __launch_bounds__(256) void k_adaln_t(Args a) {
  __shared__ __align__(16) float sm[2 * (ASLOT + 2 * SLOT) + 64];
  int bid = blockIdx.x, tid = threadIdx.x;
  if (bid < 128) adaln_t_stage(a, bid, tid, sm, sm + 2 * (ASLOT + 2 * SLOT));
  else copy_span(a, 4, bid - 128, gridDim.x - 128, tid);
}

__global__ __launch_bounds__(256) void k_swiglu(Args a) {
  __shared__ __align__(16) float sm[2 * (ASLOT + 2 * SLOT)];
  int bid = blockIdx.x, tid = threadIdx.x;
  if (bid < 256) swiglu_32(a, bid, tid, sm);
  else copy_span(a, 5, bid - 256, gridDim.x - 256, tid);
}

__global__ __launch_bounds__(256) void k_out2(Args a) {
  __shared__ __align__(16) float sm[2 * (2 * ASLOT + 2 * SLOT)];
  int bid = blockIdx.x, tid = threadIdx.x;
  if (bid < 128) out2_32(a, bid, tid, sm);
  else copy_span(a, 6, bid - 128, gridDim.x - 128, tid);
}

// ---------------------------------------------------------------------------
extern "C" void kernel_launch(void* const* d_in, const int* in_sizes, int n_in,
                              void* d_out, int out_size, void* d_ws, size_t ws_size,
                              hipStream_t stream) {
  (void)in_sizes; (void)n_in; (void)out_size; (void)ws_size;
  Args a;
  a.atom_single = (const float*)d_in[0];
  a.atom_proj   = (const float*)d_in[1];
  a.atom_pair   = (const float*)d_in[2];
  a.mask        = (const float*)d_in[3];
  a.a_sln_w  = (const float*)d_in[4];
  a.a_gate_w = (const float*)d_in[5];
  a.a_gate_b = (const float*)d_in[6];
  a.a_skip_w = (const float*)d_in[7];
  a.wq = (const float*)d_in[8];  a.bq = (const float*)d_in[9];
  a.wk = (const float*)d_in[10]; a.wv = (const float*)d_in[11];
  a.wg = (const float*)d_in[12]; a.bg = (const float*)d_in[13];
  a.wo = (const float*)d_in[14]; a.bo = (const float*)d_in[15];
  a.lnz_w = (const float*)d_in[16]; a.lnz_b = (const float*)d_in[17];
  a.wz = (const float*)d_in[18];
  a.wog = (const float*)d_in[19]; a.bog = (const float*)d_in[20];
  a.t_sln_w  = (const float*)d_in[21];
  a.t_gate_w = (const float*)d_in[22];
  a.t_gate_b = (const float*)d_in[23];
  a.t_skip_w = (const float*)d_in[24];
  a.w_sw  = (const float*)d_in[25];
  a.w_hid = (const float*)d_in[26];
  a.w_out = (const float*)d_in[27];
  a.t_wog = (const float*)d_in[28];
  a.t_bog = (const float*)d_in[29];
  a.out = (float*)d_out;

  float* ws = (float*)d_ws;
  const long NC = (long)NN * CC;
  a.s_ln_t  = (bf16*)(ws + 0 * NC);
  a.a_mat   = (bf16*)(ws + 1 * NC);
  a.qm      = (bf16*)(ws + 2 * NC);
  a.km      = (bf16*)(ws + 3 * NC);
  a.vm      = (bf16*)(ws + 4 * NC);
  a.gm      = (bf16*)(ws + 5 * NC);
  a.ogm     = (bf16*)(ws + 6 * NC);
  a.single2 = ws + 7 * NC;                 // f32 (residual base)
  a.t_mat   = (bf16*)(ws + 9 * NC);
  a.hidden  = (bf16*)(ws + 10 * NC);       // N*256 bf16 = 1 MB
  a.bias    = (bf16*)(ws + 12 * NC);       // H*N*128 bf16 = 4 MB

  // Copy slices (64ths) across 7 kernels; heavy-compute kernels carry more.
  const int cum[8] = {0, 11, 23, 37, 44, 51, 58, 64};
  for (int i = 0; i < 8; ++i) a.cut[i] = NCPTOT * (long)cum[i] / 64;

  k_adaln_a<<<GRID, 256, 0, stream>>>(a);
  k_qkvg   <<<GRID, 256, 0, stream>>>(a);
  k_attn   <<<GRID, 256, 0, stream>>>(a);
  k_out1   <<<GRID, 256, 0, stream>>>(a);
  k_adaln_t<<<GRID, 256, 0, stream>>>(a);
  k_swiglu <<<GRID, 256, 0, stream>>>(a);
  k_out2   <<<GRID, 256, 0, stream>>>(a);
}

// Round 19
// 134.517 us; speedup vs baseline: 1.0560x; 1.0560x over previous
//
#include <hip/hip_runtime.h>
#include <math.h>

#define NN 2048
#define CC 128
#define HH 8
#define DD 16
#define NKEY 128
#define INFV 1e8f
#define NPR ((long)NN * CC / 4)
#define NCPTOT (NPR + (long)NN * NN * 4)
#define SLOT 2176   // 32x68 fp32 tile (64-wide B / 64-row A)
#define ANP 36      // 32-row A tile pad
#define ASLOT 1152  // 32x36
#define GRID 2048   // verified optimum (4096 regressed: round 18)

typedef float f4 __attribute__((ext_vector_type(4)));  // native vec for nontemporal builtins
typedef unsigned short bf16;

__device__ __forceinline__ float sigm(float x) { return 1.f / (1.f + expf(-x)); }
__device__ __forceinline__ bf16 f2b(float x) {
  unsigned u = __float_as_uint(x);
  u += 0x7FFF + ((u >> 16) & 1);   // round to nearest even
  return (bf16)(u >> 16);
}
__device__ __forceinline__ float b2f(bf16 b) {
  return __uint_as_float(((unsigned)b) << 16);
}

struct Args {
  const float *atom_single, *atom_proj, *atom_pair, *mask;
  const float *a_sln_w, *a_gate_w, *a_gate_b, *a_skip_w;
  const float *wq, *bq, *wk, *wv, *wg, *bg, *wo, *bo;
  const float *lnz_w, *lnz_b, *wz, *wog, *bog;
  const float *t_sln_w, *t_gate_w, *t_gate_b, *t_skip_w;
  const float *w_sw, *w_hid, *w_out, *t_wog, *t_bog;
  float *out;
  bf16 *s_ln_t, *a_mat, *qm, *km, *vm, *gm, *ogm, *t_mat, *hidden, *bias;
  float *single2;
  long cut[8];
};

// ---------------------------------------------------------------------------
// Copy ballast (nontemporal — round-16 verified win).
// ---------------------------------------------------------------------------
__device__ __forceinline__ void copy_span(const Args& a, int s, long rb, long nb, int tid) {
  long c0 = a.cut[s], c1 = a.cut[s + 1];
  const f4* proj4 = (const f4*)a.atom_proj;
  const f4* pair4 = (const f4*)a.atom_pair;
  f4* dst = (f4*)(a.out + (long)NN * CC);
  long stride = nb * 256;
  long i = c0 + rb * 256 + tid;
  for (; i + 3 * stride < c1; i += 4 * stride) {
    long i1 = i + stride, i2 = i + 2 * stride, i3 = i + 3 * stride;
    f4 x0 = (i  < NPR) ? __builtin_nontemporal_load(&proj4[i])
                       : __builtin_nontemporal_load(&pair4[i - NPR]);
    f4 x1 = (i1 < NPR) ? __builtin_nontemporal_load(&proj4[i1])
                       : __builtin_nontemporal_load(&pair4[i1 - NPR]);
    f4 x2 = (i2 < NPR) ? __builtin_nontemporal_load(&proj4[i2])
                       : __builtin_nontemporal_load(&pair4[i2 - NPR]);
    f4 x3 = (i3 < NPR) ? __builtin_nontemporal_load(&proj4[i3])
                       : __builtin_nontemporal_load(&pair4[i3 - NPR]);
    __builtin_nontemporal_store(x0, &dst[i]);
    __builtin_nontemporal_store(x1, &dst[i1]);
    __builtin_nontemporal_store(x2, &dst[i2]);
    __builtin_nontemporal_store(x3, &dst[i3]);
  }
  for (; i < c1; i += stride) {
    f4 v = (i < NPR) ? __builtin_nontemporal_load(&proj4[i])
                     : __builtin_nontemporal_load(&pair4[i - NPR]);
    __builtin_nontemporal_store(v, &dst[i]);
  }
}

// ---------------------------------------------------------------------------
// 64x64 single-GEMM (qkvg), BK=32, DEPTH-2 prefetch; A operand bf16.
// ---------------------------------------------------------------------------
__device__ __forceinline__ void gsingle_pf(float* sm, int tid,
    const bf16* __restrict__ A1, const float* __restrict__ B1, int lda1, int ldb1, int K1,
    int r0, int c0, float acc1[4][4]) {
  float* buf0 = sm;
  float* buf1 = sm + 2 * SLOT;
  int tr = (tid >> 4) * 4, tc = (tid & 15) * 4;
  int ar = tid >> 5, ak = tid & 31;
  int bk = tid >> 6, bc = tid & 63;
  float pA[2][8], pB[2][8];
  auto LD = [&](int kb, int s) {
#pragma unroll
    for (int j = 0; j < 8; ++j) {
      pA[s][j] = b2f(A1[(long)(r0 + ar + 8 * j) * lda1 + kb + ak]);
      pB[s][j] = B1[(long)(kb + bk + 4 * j) * ldb1 + c0 + bc];
    }
  };
  auto WR = [&](float* buf, int s) {
    float* B1s_ = buf + SLOT;
#pragma unroll
    for (int j = 0; j < 8; ++j) {
      buf[ak * 68 + ar + 8 * j] = pA[s][j];
      B1s_[(bk + 4 * j) * 68 + bc] = pB[s][j];
    }
  };
  auto CMP = [&](float* cur) {
    float* As_ = cur;
    float* B1s_ = cur + SLOT;
#pragma unroll 4
    for (int k = 0; k < 32; ++k) {
      float4 a1 = *(const float4*)&As_[k * 68 + tr];
      float4 b1 = *(const float4*)&B1s_[k * 68 + tc];
      float a1v[4] = {a1.x, a1.y, a1.z, a1.w};
      float b1v[4] = {b1.x, b1.y, b1.z, b1.w};
#pragma unroll
      for (int i = 0; i < 4; ++i)
#pragma unroll
        for (int j = 0; j < 4; ++j) acc1[i][j] = fmaf(a1v[i], b1v[j], acc1[i][j]);
    }
  };
  int nk = K1 / 32;
  LD(0, 0);
  if (nk > 1) LD(32, 1);
  WR(buf0, 0);
  __syncthreads();
  for (int kt = 0; kt < nk; kt += 2) {
    if (kt + 2 < nk) LD((kt + 2) * 32, 0);
    if (kt + 1 < nk) WR(buf1, 1);
    CMP(buf0);
    __syncthreads();
    if (kt + 1 >= nk) break;
    if (kt + 3 < nk) LD((kt + 3) * 32, 1);
    if (kt + 2 < nk) WR(buf0, 0);
    CMP(buf1);
    __syncthreads();
  }
}

// ---------------------------------------------------------------------------
// 32x64 dual-GEMM, BK=32, DEPTH-2 prefetch. BF1: A1 stored bf16 (A2 always f32).
// ---------------------------------------------------------------------------
template <bool SHA, bool BF1>
__device__ __forceinline__ void gdual32(float* sm, int tid,
    const void* A1v, const float* __restrict__ B1, int lda1, int ldb1, int K1,
    const float* __restrict__ A2, const float* __restrict__ B2, int lda2, int ldb2, int K2,
    int r0, int c0, float acc1[2][4], float acc2[2][4]) {
  const int offB1 = ASLOT;
  const int offA2 = ASLOT + SLOT;
  const int offB2 = SHA ? (ASLOT + SLOT) : (2 * ASLOT + SLOT);
  const int bufsz = SHA ? (ASLOT + 2 * SLOT) : (2 * ASLOT + 2 * SLOT);
  const float* A1f = (const float*)A1v;
  const bf16* A1b = (const bf16*)A1v;
  float* buf0 = sm;
  float* buf1 = sm + bufsz;
  int tr2 = (tid >> 4) * 2, tc4 = (tid & 15) * 4;
  int ar = tid & 31, ak4 = (tid >> 5) * 4;
  int bk = tid >> 6, bc = tid & 63;
  float4 vA1[2], vA2[2];
  float pB1[2][8], pB2[2][8];

  auto LD = [&](int kb, int s, bool twof) {
    if constexpr (BF1) {
      ushort4 rw = *(const ushort4*)&A1b[(long)(r0 + ar) * lda1 + kb + ak4];
      vA1[s] = make_float4(b2f(rw.x), b2f(rw.y), b2f(rw.z), b2f(rw.w));
    } else {
      vA1[s] = *(const float4*)&A1f[(long)(r0 + ar) * lda1 + kb + ak4];
    }
#pragma unroll
    for (int j = 0; j < 8; ++j)
      pB1[s][j] = B1[(long)(kb + bk + 4 * j) * ldb1 + c0 + bc];
    if (twof) {
      if constexpr (!SHA) vA2[s] = *(const float4*)&A2[(long)(r0 + ar) * lda2 + kb + ak4];
#pragma unroll
      for (int j = 0; j < 8; ++j)
        pB2[s][j] = B2[(long)(kb + bk + 4 * j) * ldb2 + c0 + bc];
    }
  };
  auto WR = [&](float* buf, int s, bool twof) {
    float* As_ = buf;
    float* B1s_ = buf + offB1;
    As_[(ak4 + 0) * ANP + ar] = vA1[s].x;
    As_[(ak4 + 1) * ANP + ar] = vA1[s].y;
    As_[(ak4 + 2) * ANP + ar] = vA1[s].z;
    As_[(ak4 + 3) * ANP + ar] = vA1[s].w;
#pragma unroll
    for (int j = 0; j < 8; ++j) B1s_[(bk + 4 * j) * 68 + bc] = pB1[s][j];
    if (twof) {
      float* B2s_ = buf + offB2;
      if constexpr (!SHA) {
        float* A2s_ = buf + offA2;
        A2s_[(ak4 + 0) * ANP + ar] = vA2[s].x;
        A2s_[(ak4 + 1) * ANP + ar] = vA2[s].y;
        A2s_[(ak4 + 2) * ANP + ar] = vA2[s].z;
        A2s_[(ak4 + 3) * ANP + ar] = vA2[s].w;
      }
#pragma unroll
      for (int j = 0; j < 8; ++j) B2s_[(bk + 4 * j) * 68 + bc] = pB2[s][j];
    }
  };
  auto CMP = [&](float* cur, bool twoc) {
    float* As_ = cur;
    float* B1s_ = cur + offB1;
    float* A2s_ = cur + offA2;
    float* B2s_ = cur + offB2;
    if (twoc) {
#pragma unroll 4
      for (int k = 0; k < 32; ++k) {
        float2 a1 = *(const float2*)&As_[k * ANP + tr2];
        float4 b1 = *(const float4*)&B1s_[k * 68 + tc4];
        float4 b2 = *(const float4*)&B2s_[k * 68 + tc4];
        float2 a2;
        if constexpr (SHA) a2 = a1; else a2 = *(const float2*)&A2s_[k * ANP + tr2];
        float a1v[2] = {a1.x, a1.y};
        float a2v[2] = {a2.x, a2.y};
        float b1v[4] = {b1.x, b1.y, b1.z, b1.w};
        float b2v[4] = {b2.x, b2.y, b2.z, b2.w};
#pragma unroll
        for (int i = 0; i < 2; ++i)
#pragma unroll
          for (int j = 0; j < 4; ++j) {
            acc1[i][j] = fmaf(a1v[i], b1v[j], acc1[i][j]);
            acc2[i][j] = fmaf(a2v[i], b2v[j], acc2[i][j]);
          }
      }
    } else {
#pragma unroll 4
      for (int k = 0; k < 32; ++k) {
        float2 a1 = *(const float2*)&As_[k * ANP + tr2];
        float4 b1 = *(const float4*)&B1s_[k * 68 + tc4];
        float a1v[2] = {a1.x, a1.y};
        float b1v[4] = {b1.x, b1.y, b1.z, b1.w};
#pragma unroll
        for (int i = 0; i < 2; ++i)
#pragma unroll
          for (int j = 0; j < 4; ++j) acc1[i][j] = fmaf(a1v[i], b1v[j], acc1[i][j]);
      }
    }
  };

  int nk = K1 / 32;
  LD(0, 0, 0 < K2);
  if (nk > 1) LD(32, 1, 32 < K2);
  WR(buf0, 0, 0 < K2);
  __syncthreads();
  for (int kt = 0; kt < nk; kt += 2) {
    if (kt + 2 < nk) LD((kt + 2) * 32, 0, (kt + 2) * 32 < K2);
    if (kt + 1 < nk) WR(buf1, 1, (kt + 1) * 32 < K2);
    CMP(buf0, kt * 32 < K2);
    __syncthreads();
    if (kt + 1 >= nk) break;
    if (kt + 3 < nk) LD((kt + 3) * 32, 1, (kt + 3) * 32 < K2);
    if (kt + 2 < nk) WR(buf0, 0, (kt + 2) * 32 < K2);
    CMP(buf1, (kt + 1) * 32 < K2);
    __syncthreads();
  }
}

// ---------------------------------------------------------------------------
// gdual32_ln: SHA-dual-GEMM, A = LN(proj)*w_ln on the fly (round-14 verified).
// ---------------------------------------------------------------------------
__device__ __forceinline__ void gdual32_ln(float* sm, int tid,
    const float* __restrict__ proj, const float* __restrict__ w_ln,
    const float* __restrict__ B1, const float* __restrict__ B2,
    int r0, int c0, const float* sst, float acc1[2][4], float acc2[2][4]) {
  const int offB1 = ASLOT;
  const int offB2 = ASLOT + SLOT;
  const int bufsz = ASLOT + 2 * SLOT;
  float* buf0 = sm;
  float* buf1 = sm + bufsz;
  int tr2 = (tid >> 4) * 2, tc4 = (tid & 15) * 4;
  int ar = tid & 31, ak4 = (tid >> 5) * 4;
  int bk = tid >> 6, bc = tid & 63;
  float4 vA1[2];
  float pB1[2][8], pB2[2][8];

  auto LD = [&](int kb, int s) {
    float4 raw = *(const float4*)&proj[(long)(r0 + ar) * CC + kb + ak4];
    float4 wv = *(const float4*)&w_ln[kb + ak4];
    float mu = sst[2 * ar], rs = sst[2 * ar + 1];
    vA1[s].x = (raw.x - mu) * rs * wv.x;
    vA1[s].y = (raw.y - mu) * rs * wv.y;
    vA1[s].z = (raw.z - mu) * rs * wv.z;
    vA1[s].w = (raw.w - mu) * rs * wv.w;
#pragma unroll
    for (int j = 0; j < 8; ++j) {
      pB1[s][j] = B1[(long)(kb + bk + 4 * j) * CC + c0 + bc];
      pB2[s][j] = B2[(long)(kb + bk + 4 * j) * CC + c0 + bc];
    }
  };
  auto WR = [&](float* buf, int s) {
    float* B1s_ = buf + offB1;
    float* B2s_ = buf + offB2;
    buf[(ak4 + 0) * ANP + ar] = vA1[s].x;
    buf[(ak4 + 1) * ANP + ar] = vA1[s].y;
    buf[(ak4 + 2) * ANP + ar] = vA1[s].z;
    buf[(ak4 + 3) * ANP + ar] = vA1[s].w;
#pragma unroll
    for (int j = 0; j < 8; ++j) {
      B1s_[(bk + 4 * j) * 68 + bc] = pB1[s][j];
      B2s_[(bk + 4 * j) * 68 + bc] = pB2[s][j];
    }
  };
  auto CMP = [&](float* cur) {
    float* As_ = cur;
    float* B1s_ = cur + offB1;
    float* B2s_ = cur + offB2;
#pragma unroll 4
    for (int k = 0; k < 32; ++k) {
      float2 a1 = *(const float2*)&As_[k * ANP + tr2];
      float4 b1 = *(const float4*)&B1s_[k * 68 + tc4];
      float4 b2 = *(const float4*)&B2s_[k * 68 + tc4];
      float a1v[2] = {a1.x, a1.y};
      float b1v[4] = {b1.x, b1.y, b1.z, b1.w};
      float b2v[4] = {b2.x, b2.y, b2.z, b2.w};
#pragma unroll
      for (int i = 0; i < 2; ++i)
#pragma unroll
        for (int j = 0; j < 4; ++j) {
          acc1[i][j] = fmaf(a1v[i], b1v[j], acc1[i][j]);
          acc2[i][j] = fmaf(a1v[i], b2v[j], acc2[i][j]);
        }
    }
  };

  LD(0, 0);
  LD(32, 1);
  WR(buf0, 0);
  __syncthreads();
  LD(64, 0);
  WR(buf1, 1);
  CMP(buf0);
  __syncthreads();
  LD(96, 1);
  WR(buf0, 0);
  CMP(buf1);
  __syncthreads();
  WR(buf1, 1);
  CMP(buf0);
  __syncthreads();
  CMP(buf1);
  __syncthreads();
}

// ---------------------------------------------------------------------------
// Stage bodies
// ---------------------------------------------------------------------------
__device__ __forceinline__ void bias_stage(const Args& a, long lo, long hi,
                                           int bid, int nb, int tid, float* sm) {
  float* swz = sm;
  float* swn = sm + 128;
  float* sbn = sm + 144;
  if (tid < 128) swz[tid] = a.wz[tid];
  else if (tid < 144) swn[tid - 128] = a.lnz_w[tid - 128];
  else if (tid < 160) sbn[tid - 144] = a.lnz_b[tid - 144];
  __syncthreads();
  for (long e = lo + bid * 256 + tid; e < hi; e += (long)nb * 256) {
    int q = (int)(e >> 7), kk = (int)(e & 127);
    int k = (q >> 5) * 32 - 48 + kk;
    float o[HH];
    if (k >= 0 && k < NN) {
      const float4* p = (const float4*)(a.atom_pair + ((long)q * NN + k) * 16);
      float4 x0 = p[0], x1 = p[1], x2 = p[2], x3 = p[3];
      float x[16] = {x0.x, x0.y, x0.z, x0.w, x1.x, x1.y, x1.z, x1.w,
                     x2.x, x2.y, x2.z, x2.w, x3.x, x3.y, x3.z, x3.w};
      float s = 0.f, ss = 0.f;
#pragma unroll
      for (int c = 0; c < 16; ++c) { s += x[c]; ss += x[c] * x[c]; }
      float mu = s * (1.f / 16.f);
      float r = rsqrtf(ss * (1.f / 16.f) - mu * mu + 1e-5f);
#pragma unroll
      for (int h = 0; h < HH; ++h) o[h] = 0.f;
#pragma unroll
      for (int c = 0; c < 16; ++c) {
        float y = (x[c] - mu) * r * swn[c] + sbn[c];
#pragma unroll
        for (int h = 0; h < HH; ++h) o[h] = fmaf(y, swz[c * HH + h], o[h]);
      }
      float mb = INFV * (a.mask[k] - 1.f);
#pragma unroll
      for (int h = 0; h < HH; ++h) o[h] += mb;
    } else {
#pragma unroll
      for (int h = 0; h < HH; ++h) o[h] = -INFV;
    }
#pragma unroll
    for (int h = 0; h < HH; ++h) a.bias[(long)h * NN * NKEY + e] = f2b(o[h]);
  }
}

// adaln_a with inline LN (round-14 verified); bf16 outputs.
__device__ __forceinline__ void adaln_a_ln(const Args& a, int bid, int tid,
                                           float* sm, float* sst) {
  int r0 = (bid & 63) * 32, c0 = (bid >> 6) * 64;
  {
    int row = tid >> 3, cg = (tid & 7) * 16;
    const float* sp = a.atom_proj + (long)(r0 + row) * CC + cg;
    const float* ss_ = a.atom_single + (long)(r0 + row) * CC + cg;
    float s1 = 0.f, q1 = 0.f, s2 = 0.f, q2 = 0.f;
#pragma unroll
    for (int j = 0; j < 4; ++j) {
      float4 v = *(const float4*)(sp + j * 4);
      s1 += v.x + v.y + v.z + v.w;
      q1 += v.x * v.x + v.y * v.y + v.z * v.z + v.w * v.w;
      float4 u = *(const float4*)(ss_ + j * 4);
      s2 += u.x + u.y + u.z + u.w;
      q2 += u.x * u.x + u.y * u.y + u.z * u.z + u.w * u.w;
    }
#pragma unroll
    for (int m = 1; m < 8; m <<= 1) {
      s1 += __shfl_xor(s1, m); q1 += __shfl_xor(q1, m);
      s2 += __shfl_xor(s2, m); q2 += __shfl_xor(q2, m);
    }
    if ((tid & 7) == 0) {
      float mu1 = s1 * (1.f / CC);
      sst[2 * row] = mu1;
      sst[2 * row + 1] = rsqrtf(q1 * (1.f / CC) - mu1 * mu1 + 1e-5f);
      float mu2 = s2 * (1.f / CC);
      sst[64 + 2 * row] = mu2;
      sst[64 + 2 * row + 1] = rsqrtf(q2 * (1.f / CC) - mu2 * mu2 + 1e-5f);
    }
  }
  __syncthreads();
  float acc1[2][4] = {{0}}, acc2[2][4] = {{0}};
  gdual32_ln(sm, tid, a.atom_proj, a.a_sln_w, a.a_gate_w, a.a_skip_w,
             r0, c0, sst, acc1, acc2);
  int tr2 = (tid >> 4) * 2, tc4 = (tid & 15) * 4;
#pragma unroll
  for (int i = 0; i < 2; ++i) {
    long r = r0 + tr2 + i;
    float mup = sst[2 * (tr2 + i)], rsp = sst[2 * (tr2 + i) + 1];
    float mus = sst[64 + 2 * (tr2 + i)], rss = sst[64 + 2 * (tr2 + i) + 1];
    float4 sv = *(const float4*)(a.atom_single + r * CC + c0 + tc4);
    float4 pv = *(const float4*)(a.atom_proj + r * CC + c0 + tc4);
    float4 wt = *(const float4*)(a.t_sln_w + c0 + tc4);
    float lnm[4] = {(sv.x - mus) * rss, (sv.y - mus) * rss,
                    (sv.z - mus) * rss, (sv.w - mus) * rss};
    float lnp[4] = {(pv.x - mup) * rsp, (pv.y - mup) * rsp,
                    (pv.z - mup) * rsp, (pv.w - mup) * rsp};
    float wtv[4] = {wt.x, wt.y, wt.z, wt.w};
    float o[4];
#pragma unroll
    for (int j = 0; j < 4; ++j)
      o[j] = sigm(acc1[i][j] + a.a_gate_b[c0 + tc4 + j]) * lnm[j] + acc2[i][j];
    *(ushort4*)(a.a_mat + r * CC + c0 + tc4) =
        make_ushort4(f2b(o[0]), f2b(o[1]), f2b(o[2]), f2b(o[3]));
    *(ushort4*)(a.s_ln_t + r * CC + c0 + tc4) =
        make_ushort4(f2b(lnp[0] * wtv[0]), f2b(lnp[1] * wtv[1]),
                     f2b(lnp[2] * wtv[2]), f2b(lnp[3] * wtv[3]));
  }
}

// adaln_t: A = s_ln_t (bf16), gate multiplier = inline LN(single2 f32).
__device__ __forceinline__ void adaln_t_stage(const Args& a, int bid, int tid,
                                              float* sm, float* sst) {
  int r0 = (bid & 63) * 32, c0 = (bid >> 6) * 64;
  {
    int row = tid >> 3, cg = (tid & 7) * 16;
    const float* src = a.single2 + (long)(r0 + row) * CC + cg;
    float s = 0.f, ss = 0.f;
#pragma unroll
    for (int j = 0; j < 4; ++j) {
      float4 v = *(const float4*)(src + j * 4);
      s += v.x + v.y + v.z + v.w;
      ss += v.x * v.x + v.y * v.y + v.z * v.z + v.w * v.w;
    }
#pragma unroll
    for (int m = 1; m < 8; m <<= 1) { s += __shfl_xor(s, m); ss += __shfl_xor(ss, m); }
    if ((tid & 7) == 0) {
      float mu = s * (1.f / CC);
      sst[2 * row] = mu;
      sst[2 * row + 1] = rsqrtf(ss * (1.f / CC) - mu * mu + 1e-5f);
    }
  }
  float acc1[2][4] = {{0}}, acc2[2][4] = {{0}};
  gdual32<true, true>(sm, tid, a.s_ln_t, a.t_gate_w, 128, 128, 128,
                      nullptr, a.t_skip_w, 128, 128, 128, r0, c0, acc1, acc2);
  int tr2 = (tid >> 4) * 2, tc4 = (tid & 15) * 4;
#pragma unroll
  for (int i = 0; i < 2; ++i) {
    long r = r0 + tr2 + i;
    float mu = sst[2 * (tr2 + i)], rr = sst[2 * (tr2 + i) + 1];
    float4 sv = *(const float4*)(a.single2 + r * CC + c0 + tc4);
    float lv[4] = {(sv.x - mu) * rr, (sv.y - mu) * rr, (sv.z - mu) * rr, (sv.w - mu) * rr};
    float o[4];
#pragma unroll
    for (int j = 0; j < 4; ++j)
      o[j] = sigm(acc1[i][j] + a.t_gate_b[c0 + tc4 + j]) * lv[j] + acc2[i][j];
    *(ushort4*)(a.t_mat + r * CC + c0 + tc4) =
        make_ushort4(f2b(o[0]), f2b(o[1]), f2b(o[2]), f2b(o[3]));
  }
}

__device__ __forceinline__ void gemm4_stage(const Args& a, int bid, int tid, float* sm) {
  int r0 = (bid & 31) * 64;
  int cg4 = (bid >> 5) * 64;
  int mat = cg4 >> 7;
  int c0 = cg4 & 127;
  const float* B = (mat == 0) ? a.wq : (mat == 1) ? a.wk : (mat == 2) ? a.wv : a.wg;
  float acc[4][4] = {{0}};
  gsingle_pf(sm, tid, a.a_mat, B, 128, 128, 128, r0, c0, acc);
  bf16* outp = (mat == 0) ? a.qm : (mat == 1) ? a.km : (mat == 2) ? a.vm : a.gm;
  int tr = (tid >> 4) * 4, tc = (tid & 15) * 4;
#pragma unroll
  for (int i = 0; i < 4; ++i) {
    long r = r0 + tr + i;
    float o[4];
#pragma unroll
    for (int j = 0; j < 4; ++j) {
      float x = acc[i][j];
      if (mat == 0) x += a.bq[c0 + tc + j];
      if (mat == 3) x = sigm(x + a.bg[c0 + tc + j]);
      o[j] = x;
    }
    *(ushort4*)(outp + r * CC + c0 + tc) =
        make_ushort4(f2b(o[0]), f2b(o[1]), f2b(o[2]), f2b(o[3]));
  }
}

__device__ __forceinline__ void attn_unit(const Args& a, int u, int tid, float* sm) {
  int w = u & 63, h = u >> 6;
  int q0 = w * 32, k0 = w * 32 - 48;
  float* Qs = sm;
  float* Ks = sm + 544;
  float* Vs = sm + 3104;
  float* Ps = sm + 5664;
  for (int i = tid; i < 32 * 16; i += 256) {
    int qi = i >> 4, d = i & 15;
    Qs[qi * 17 + d] = b2f(a.qm[(long)(q0 + qi) * CC + h * DD + d]);
  }
  for (int i = tid; i < 128 * 16; i += 256) {
    int kk = i >> 4, d = i & 15;
    int k = k0 + kk;
    bool ok = (k >= 0 && k < NN);
    Ks[kk * 20 + d] = ok ? b2f(a.km[(long)k * CC + h * DD + d]) : 0.f;
    Vs[kk * 20 + d] = ok ? b2f(a.vm[(long)k * CC + h * DD + d]) : 0.f;
  }
  __syncthreads();
  int qi = tid >> 3, kg = tid & 7;
  const bf16* brow = a.bias + (long)h * NN * NKEY + (long)(q0 + qi) * NKEY;
  float qreg[16];
#pragma unroll
  for (int d = 0; d < 16; ++d) qreg[d] = Qs[qi * 17 + d];
  float l[16];
#pragma unroll
  for (int j = 0; j < 16; ++j) {
    int kk = kg + 8 * j;
    const float4* kr = (const float4*)&Ks[kk * 20];
    float4 k0v = kr[0], k1v = kr[1], k2v = kr[2], k3v = kr[3];
    float acc = 0.f;
    acc = fmaf(qreg[0], k0v.x, acc);  acc = fmaf(qreg[1], k0v.y, acc);
    acc = fmaf(qreg[2], k0v.z, acc);  acc = fmaf(qreg[3], k0v.w, acc);
    acc = fmaf(qreg[4], k1v.x, acc);  acc = fmaf(qreg[5], k1v.y, acc);
    acc = fmaf(qreg[6], k1v.z, acc);  acc = fmaf(qreg[7], k1v.w, acc);
    acc = fmaf(qreg[8], k2v.x, acc);  acc = fmaf(qreg[9], k2v.y, acc);
    acc = fmaf(qreg[10], k2v.z, acc); acc = fmaf(qreg[11], k2v.w, acc);
    acc = fmaf(qreg[12], k3v.x, acc); acc = fmaf(qreg[13], k3v.y, acc);
    acc = fmaf(qreg[14], k3v.z, acc); acc = fmaf(qreg[15], k3v.w, acc);
    l[j] = acc * 0.25f + b2f(brow[kk]);
  }
  float m = l[0];
#pragma unroll
  for (int j = 1; j < 16; ++j) m = fmaxf(m, l[j]);
#pragma unroll
  for (int mm = 1; mm < 8; mm <<= 1) m = fmaxf(m, __shfl_xor(m, mm));
  float sum = 0.f;
#pragma unroll
  for (int j = 0; j < 16; ++j) { l[j] = expf(l[j] - m); sum += l[j]; }
#pragma unroll
  for (int mm = 1; mm < 8; mm <<= 1) sum += __shfl_xor(sum, mm);
  float inv = 1.f / sum;
#pragma unroll
  for (int j = 0; j < 16; ++j) Ps[qi * 132 + kg + 8 * j] = l[j] * inv;
  __syncthreads();
  int d0 = tid & 7;
  float o0 = 0.f, o1 = 0.f;
#pragma unroll 8
  for (int kk = 0; kk < 128; ++kk) {
    float p = Ps[qi * 132 + kk];
    o0 = fmaf(p, Vs[kk * 20 + d0], o0);
    o1 = fmaf(p, Vs[kk * 20 + d0 + 8], o1);
  }
  long base = (long)(q0 + qi) * CC + h * DD;
  a.ogm[base + d0] = f2b(o0 * b2f(a.gm[base + d0]));
  a.ogm[base + d0 + 8] = f2b(o1 * b2f(a.gm[base + d0 + 8]));
}

__device__ __forceinline__ void out1_32(const Args& a, int bid, int tid, float* sm) {
  int r0 = (bid & 63) * 32, c0 = (bid >> 6) * 64;
  float accX[2][4] = {{0}}, accW[2][4] = {{0}};
  gdual32<false, true>(sm, tid, a.ogm, a.wo, 128, 128, 128,
                       a.atom_proj, a.wog, 128, 128, 128, r0, c0, accX, accW);
  int tr2 = (tid >> 4) * 2, tc4 = (tid & 15) * 4;
#pragma unroll
  for (int i = 0; i < 2; ++i) {
    long r = r0 + tr2 + i;
    float4 sv = *(const float4*)(a.atom_single + r * CC + c0 + tc4);
    float s[4] = {sv.x, sv.y, sv.z, sv.w};
    float o[4];
#pragma unroll
    for (int j = 0; j < 4; ++j) {
      int c = c0 + tc4 + j;
      o[j] = s[j] + sigm(accW[i][j] + a.bog[c]) * (accX[i][j] + a.bo[c]);
    }
    *(float4*)(a.single2 + r * CC + c0 + tc4) = make_float4(o[0], o[1], o[2], o[3]);
  }
}

__device__ __forceinline__ void swiglu_32(const Args& a, int bid, int tid, float* sm) {
  int r0 = (bid & 63) * 32, c0 = (bid >> 6) * 64;
  float acc1[2][4] = {{0}}, acc2[2][4] = {{0}};
  gdual32<true, true>(sm, tid, a.t_mat, a.w_sw, 128, 256, 128,
                      nullptr, a.w_hid, 128, 256, 128, r0, c0, acc1, acc2);
  int tr2 = (tid >> 4) * 2, tc4 = (tid & 15) * 4;
#pragma unroll
  for (int i = 0; i < 2; ++i) {
    long r = r0 + tr2 + i;
    float o[4];
#pragma unroll
    for (int j = 0; j < 4; ++j) {
      float x = acc1[i][j];
      o[j] = x * sigm(x) * acc2[i][j];
    }
    *(ushort4*)(a.hidden + r * 256 + c0 + tc4) =
        make_ushort4(f2b(o[0]), f2b(o[1]), f2b(o[2]), f2b(o[3]));
  }
}

__device__ __forceinline__ void out2_32(const Args& a, int bid, int tid, float* sm) {
  int r0 = (bid & 63) * 32, c0 = (bid >> 6) * 64;
  float accX[2][4] = {{0}}, accW[2][4] = {{0}};
  gdual32<false, true>(sm, tid, a.hidden, a.w_out, 256, 128, 256,
                       a.atom_proj, a.t_wog, 128, 128, 128, r0, c0, accX, accW);
  int tr2 = (tid >> 4) * 2, tc4 = (tid & 15) * 4;
#pragma unroll
  for (int i = 0; i < 2; ++i) {
    long r = r0 + tr2 + i;
    float4 sv = *(const float4*)(a.single2 + r * CC + c0 + tc4);
    float s[4] = {sv.x, sv.y, sv.z, sv.w};
    float o[4];
#pragma unroll
    for (int j = 0; j < 4; ++j) {
      int c = c0 + tc4 + j;
      o[j] = s[j] + sigm(accW[i][j] + a.t_bog[c]) * accX[i][j];
    }
    *(float4*)(a.out + r * CC + c0 + tc4) = make_float4(o[0], o[1], o[2], o[3]);
  }
}

// ---------------------------------------------------------------------------
// 7 kernels (round-17 verified structure, GRID=2048).
// ---------------------------------------------------------------------------
#define BIAS_TOT ((long)NN * NKEY)
#define BIAS_H (BIAS_TOT / 2)

__global__ __launch_bounds__(256) void k_adaln_a(Args a) {
  __shared__ __align__(16) float sm[2 * (ASLOT + 2 * SLOT) + 128];
  int bid = blockIdx.x, tid = threadIdx.x;
  if (bid < 128) adaln_a_ln(a, bid, tid, sm, sm + 2 * (ASLOT + 2 * SLOT));
  else if (bid < 256) bias_stage(a, 0, BIAS_H, bid - 128, 128, tid, sm);
  else copy_span(a, 0, bid - 256, gridDim.x - 256, tid);
}

__global__ __launch_bounds__(256) void k_qkvg(Args a) {
  __shared__ __align__(16) float sm[2 * 2 * SLOT];
  int bid = blockIdx.x, tid = threadIdx.x;
  if (bid < 256) gemm4_stage(a, bid, tid, sm);
  else if (bid < 384) bias_stage(a, BIAS_H, BIAS_TOT, bid - 256, 128, tid, sm);
  else copy_span(a, 1, bid - 384, gridDim.x - 384, tid);
}

__global__ __launch_bounds__(256) void k_attn(Args a) {
  __shared__ __align__(16) float sm[9888];
  int bid = blockIdx.x, tid = threadIdx.x;
  if (bid < 512) attn_unit(a, bid, tid, sm);
  else copy_span(a, 2, bid - 512, gridDim.x - 512, tid);
}

__global__ __launch_bounds__(256) void k_out1(Args a) {
  __shared__ __align__(16) float sm[2 * (2 * ASLOT + 2 * SLOT)];
  int bid = blockIdx.x, tid = threadIdx.x;
  if (bid < 128) out1_32(a, bid, tid, sm);
  else copy_span(a, 3, bid - 128, gridDim.x - 128, tid);
}

__global__ __launch_bounds__(256) void k_adaln_t(Args a) {
  __shared__ __align__(16) float sm[2 * (ASLOT + 2 * SLOT) + 64];
  int bid = blockIdx.x, tid = threadIdx.x;
  if (bid < 128) adaln_t_stage(a, bid, tid, sm, sm + 2 * (ASLOT + 2 * SLOT));
  else copy_span(a, 4, bid - 128, gridDim.x - 128, tid);
}

__global__ __launch_bounds__(256) void k_swiglu(Args a) {
  __shared__ __align__(16) float sm[2 * (ASLOT + 2 * SLOT)];
  int bid = blockIdx.x, tid = threadIdx.x;
  if (bid < 256) swiglu_32(a, bid, tid, sm);
  else copy_span(a, 5, bid - 256, gridDim.x - 256, tid);
}

__global__ __launch_bounds__(256) void k_out2(Args a) {
  __shared__ __align__(16) float sm[2 * (2 * ASLOT + 2 * SLOT)];
  int bid = blockIdx.x, tid = threadIdx.x;
  if (bid < 128) out2_32(a, bid, tid, sm);
  else copy_span(a, 6, bid - 128, gridDim.x - 128, tid);
}

// ---------------------------------------------------------------------------
extern "C" void kernel_launch(void* const* d_in, const int* in_sizes, int n_in,
                              void* d_out, int out_size, void* d_ws, size_t ws_size,
                              hipStream_t stream) {
  (void)in_sizes; (void)n_in; (void)out_size; (void)ws_size;
  Args a;
  a.atom_single = (const float*)d_in[0];
  a.atom_proj   = (const float*)d_in[1];
  a.atom_pair   = (const float*)d_in[2];
  a.mask        = (const float*)d_in[3];
  a.a_sln_w  = (const float*)d_in[4];
  a.a_gate_w = (const float*)d_in[5];
  a.a_gate_b = (const float*)d_in[6];
  a.a_skip_w = (const float*)d_in[7];
  a.wq = (const float*)d_in[8];  a.bq = (const float*)d_in[9];
  a.wk = (const float*)d_in[10]; a.wv = (const float*)d_in[11];
  a.wg = (const float*)d_in[12]; a.bg = (const float*)d_in[13];
  a.wo = (const float*)d_in[14]; a.bo = (const float*)d_in[15];
  a.lnz_w = (const float*)d_in[16]; a.lnz_b = (const float*)d_in[17];
  a.wz = (const float*)d_in[18];
  a.wog = (const float*)d_in[19]; a.bog = (const float*)d_in[20];
  a.t_sln_w  = (const float*)d_in[21];
  a.t_gate_w = (const float*)d_in[22];
  a.t_gate_b = (const float*)d_in[23];
  a.t_skip_w = (const float*)d_in[24];
  a.w_sw  = (const float*)d_in[25];
  a.w_hid = (const float*)d_in[26];
  a.w_out = (const float*)d_in[27];
  a.t_wog = (const float*)d_in[28];
  a.t_bog = (const float*)d_in[29];
  a.out = (float*)d_out;

  float* ws = (float*)d_ws;
  const long NC = (long)NN * CC;
  a.s_ln_t  = (bf16*)(ws + 0 * NC);
  a.a_mat   = (bf16*)(ws + 1 * NC);
  a.qm      = (bf16*)(ws + 2 * NC);
  a.km      = (bf16*)(ws + 3 * NC);
  a.vm      = (bf16*)(ws + 4 * NC);
  a.gm      = (bf16*)(ws + 5 * NC);
  a.ogm     = (bf16*)(ws + 6 * NC);
  a.single2 = ws + 7 * NC;                 // f32 (residual base)
  a.t_mat   = (bf16*)(ws + 9 * NC);
  a.hidden  = (bf16*)(ws + 10 * NC);       // N*256 bf16 = 1 MB
  a.bias    = (bf16*)(ws + 12 * NC);       // H*N*128 bf16 = 4 MB

  // Copy slices (64ths) across 7 kernels; heavy-compute kernels carry more.
  const int cum[8] = {0, 11, 23, 37, 44, 51, 58, 64};
  for (int i = 0; i < 8; ++i) a.cut[i] = NCPTOT * (long)cum[i] / 64;

  k_adaln_a<<<GRID, 256, 0, stream>>>(a);
  k_qkvg   <<<GRID, 256, 0, stream>>>(a);
  k_attn   <<<GRID, 256, 0, stream>>>(a);
  k_out1   <<<GRID, 256, 0, stream>>>(a);
  k_adaln_t<<<GRID, 256, 0, stream>>>(a);
  k_swiglu <<<GRID, 256, 0, stream>>>(a);
  k_out2   <<<GRID, 256, 0, stream>>>(a);
}